// Round 2
// baseline (531.908 us; speedup 1.0000x reference)
//
#include <hip/hip_runtime.h>
#include <hip/hip_bf16.h>
#include <cstdint>

// MLA: B=2, S=4096, D=1024, H=4, dk=d_kv=256, scale=1/16.
// bf16 MFMA everywhere: QKV fused NT GEMM -> flash attention (K/V shared
// across heads) -> O projection (fp32 out).

typedef __bf16 bf16_t;
typedef __bf16 bf16x8 __attribute__((ext_vector_type(8)));
typedef float f32x4 __attribute__((ext_vector_type(4)));
typedef unsigned short u16;
typedef u16 u16x8 __attribute__((ext_vector_type(8)));

#define DEVI static __device__ __forceinline__

constexpr int S_LEN = 4096;
constexpr int NQKV = 1536;   // Q(1024) | K(256) | V(256)
constexpr int DMODEL = 1024;
constexpr int DKV = 256;
constexpr float SM_SCALE = 0.0625f;  // 1/sqrt(256)

DEVI void gload_lds16(const bf16_t* g, bf16_t* l) {
  __builtin_amdgcn_global_load_lds(
      (const __attribute__((address_space(1))) void*)g,
      (__attribute__((address_space(3))) void*)l, 16, 0, 0);
}

// ---------------- fp32 -> bf16 convert (vectorized) ----------------
__global__ void cvt_bf16(const float4* __restrict__ src, bf16_t* __restrict__ dst, int n4) {
  int i = blockIdx.x * 256 + threadIdx.x;
  if (i < n4) {
    float4 v = src[i];
    bf16_t o[4] = { (bf16_t)v.x, (bf16_t)v.y, (bf16_t)v.z, (bf16_t)v.w };
    *reinterpret_cast<uint64_t*>(dst + (size_t)i * 4) = *reinterpret_cast<uint64_t*>(o);
  }
}

// ---------------- NT GEMM: C[M,N] = A[M,K] * Bw[N,K]^T ----------------
// 128x128 block, BK=32, 4 waves (each 64x64 = 4x4 frags of 16x16x32),
// global_load_lds width-16 staging, double-buffered LDS, 2 barriers/step.
template <typename OutT>
__global__ __launch_bounds__(256) void gemm_nt(
    const bf16_t* __restrict__ A, const bf16_t* __restrict__ Bw,
    OutT* __restrict__ C, int M, int N, int K) {
  __shared__ __align__(16) bf16_t lA[2][128 * 32];
  __shared__ __align__(16) bf16_t lB[2][128 * 32];
  const int tid = threadIdx.x;
  const int lane = tid & 63;
  const int w = tid >> 6;
  const int r16 = lane & 15, hi = lane >> 4;
  const int wm = (w >> 1) * 64, wn = (w & 1) * 64;
  const long bm = (long)blockIdx.x * 128;
  const long bn = (long)blockIdx.y * 128;

  f32x4 acc[4][4] = {};

  auto stageAB = [&](int buf, int k0) {
#pragma unroll
    for (int c = 0; c < 2; ++c) {
      const int chunk = w + c * 4;           // 8 chunks of 1KB per tile
      const int row = chunk * 16 + (lane >> 2);
      const int kk = (lane & 3) * 8;
      gload_lds16(A + (bm + row) * (long)K + k0 + kk, &lA[buf][chunk * 512]);
      gload_lds16(Bw + (bn + row) * (long)K + k0 + kk, &lB[buf][chunk * 512]);
    }
  };

  const int nk = K >> 5;
  stageAB(0, 0);
  for (int kt = 0; kt < nk; ++kt) {
    const int cur = kt & 1;
    __syncthreads();                       // staging of cur complete (vmcnt drain)
    if (kt + 1 < nk) stageAB(cur ^ 1, (kt + 1) * 32);
    const bf16_t* la = lA[cur];
    const bf16_t* lb = lB[cur];
    bf16x8 af[4], bq[4];
#pragma unroll
    for (int i = 0; i < 4; ++i)
      af[i] = *(const bf16x8*)&la[(wm + i * 16 + r16) * 32 + hi * 8];
#pragma unroll
    for (int j = 0; j < 4; ++j)
      bq[j] = *(const bf16x8*)&lb[(wn + j * 16 + r16) * 32 + hi * 8];
#pragma unroll
    for (int i = 0; i < 4; ++i)
#pragma unroll
      for (int j = 0; j < 4; ++j)
        acc[i][j] = __builtin_amdgcn_mfma_f32_16x16x32_bf16(af[i], bq[j], acc[i][j], 0, 0, 0);
    __syncthreads();                       // all reads of cur done before restage
  }

#pragma unroll
  for (int i = 0; i < 4; ++i)
#pragma unroll
    for (int j = 0; j < 4; ++j)
#pragma unroll
      for (int r = 0; r < 4; ++r) {
        long row = bm + wm + i * 16 + hi * 4 + r;
        long col = bn + wn + j * 16 + r16;
        C[row * N + col] = (OutT)acc[i][j][r];
      }
}

// ---------------- V transpose: Vt[b][d][t] = QKV[b*S+t][1280+d] ----------------
__global__ void transpose_v(const bf16_t* __restrict__ QKV, bf16_t* __restrict__ Vt) {
  __shared__ u16 tile[64][68];
  const int t0 = blockIdx.x * 64, d0 = blockIdx.y * 64, b = blockIdx.z;
  const int tid = threadIdx.x;
  const int r = tid >> 3, c8 = tid & 7;
#pragma unroll
  for (int p = 0; p < 2; ++p) {
    const int tr = p * 32 + r;
    const u16* gp = (const u16*)QKV + (size_t)(b * S_LEN + t0 + tr) * NQKV + 1280 + d0 + c8 * 8;
    u16x8 v = *(const u16x8*)gp;
#pragma unroll
    for (int j = 0; j < 8; ++j) tile[tr][c8 * 8 + j] = v[j];
  }
  __syncthreads();
#pragma unroll
  for (int p = 0; p < 2; ++p) {
    const int dr = p * 32 + r;
    u16x8 v;
#pragma unroll
    for (int j = 0; j < 8; ++j) v[j] = tile[c8 * 8 + j][dr];
    *(u16x8*)((u16*)Vt + (size_t)(b * DKV + d0 + dr) * S_LEN + t0 + c8 * 8) = v;
  }
}

// ---------------- Flash attention ----------------
// 1D grid of 256 blocks; bh = id%8 so all q-blocks of one (b,h) share an XCD
// (dispatch round-robins id->XCD), making its 4MB K/V slice L2-resident.
// Block: 128 q-rows, 4 waves x 32 rows. K/V tiles of 64 t-rows double-buffered
// in LDS, XOR-swizzled (byte ^= (row&7)<<4) with inverse-swizzled global source
// so global_load_lds (linear dest) + swizzled reads agree (guide rule #21).
__global__ __launch_bounds__(256, 1) void mla_attn(
    const bf16_t* __restrict__ QKV, const bf16_t* __restrict__ Vt,
    bf16_t* __restrict__ O) {
  __shared__ __align__(16) bf16_t lK[2][64 * 256];   // [t][d] swizzled, 32KB each
  __shared__ __align__(16) bf16_t lV[2][256 * 64];   // [d][t] swizzled, 32KB each
  __shared__ __align__(16) bf16_t lP[128 * 64];      // [q][t] swizzled, 16KB

  const int tid = threadIdx.x, lane = tid & 63, w = tid >> 6;
  const int r16 = lane & 15, hi = lane >> 4;
  const int bh = blockIdx.x & 7;          // XCD-locality: same (b,h) -> same XCD
  const int b = bh >> 2, h = bh & 3;
  const int q0 = (blockIdx.x >> 3) * 128;

  auto stageK = [&](int buf, int t0) {
#pragma unroll
    for (int c = 0; c < 8; ++c) {
      const int chunk = w * 8 + c;               // 32 chunks of 1KB (2 rows)
      const int row = chunk * 2 + (lane >> 5);
      const int gslot = (lane & 31) ^ (row & 7); // inverse swizzle on source
      gload_lds16(QKV + ((long)(b * S_LEN + t0 + row)) * NQKV + 1024 + gslot * 8,
                  &lK[buf][chunk * 512]);
    }
  };
  auto stageV = [&](int buf, int t0) {
#pragma unroll
    for (int c = 0; c < 8; ++c) {
      const int chunk = w * 8 + c;               // 32 chunks of 1KB (8 d-rows)
      const int row = chunk * 8 + (lane >> 3);
      const int gslot = (lane & 7) ^ (row & 7);
      gload_lds16(Vt + ((long)(b * DKV + row)) * S_LEN + t0 + gslot * 8,
                  &lV[buf][chunk * 512]);
    }
  };

  // Q fragments in registers: 32 rows/wave, full dk=256
  bf16x8 qa[2][8];
#pragma unroll
  for (int rf = 0; rf < 2; ++rf) {
    const bf16_t* qrow = QKV + ((long)(b * S_LEN + q0 + w * 32 + rf * 16 + r16)) * NQKV + h * DKV;
#pragma unroll
    for (int ks = 0; ks < 8; ++ks) qa[rf][ks] = *(const bf16x8*)(qrow + ks * 32 + hi * 8);
  }

  f32x4 oacc[2][16] = {};
  float mr[2][4], lr[2][4];
#pragma unroll
  for (int rf = 0; rf < 2; ++rf)
#pragma unroll
    for (int r = 0; r < 4; ++r) { mr[rf][r] = -3.0e38f; lr[rf][r] = 0.f; }

  stageK(0, 0);
  stageV(0, 0);

  const int nst = S_LEN / 64;
  for (int kt = 0; kt < nst; ++kt) {
    const int cur = kt & 1;
    __syncthreads();
    if (kt + 1 < nst) { stageK(cur ^ 1, (kt + 1) * 64); stageV(cur ^ 1, (kt + 1) * 64); }

    // ---- S = Q K^T (rows q, cols t) ----
    f32x4 sf[2][4] = {};
    const char* kbase = (const char*)lK[cur];
#pragma unroll
    for (int tf = 0; tf < 4; ++tf) {
      const int row = tf * 16 + r16;
      const int rowoff = row * 512;
      const int sw = (row & 7) << 4;
#pragma unroll
      for (int ks = 0; ks < 8; ++ks) {
        bf16x8 kf = *(const bf16x8*)(kbase + rowoff + ((ks * 64 + hi * 16) ^ sw));
        sf[0][tf] = __builtin_amdgcn_mfma_f32_16x16x32_bf16(qa[0][ks], kf, sf[0][tf], 0, 0, 0);
        sf[1][tf] = __builtin_amdgcn_mfma_f32_16x16x32_bf16(qa[1][ks], kf, sf[1][tf], 0, 0, 0);
      }
    }

    // ---- online softmax (D-layout: lane holds row hi*4+r, col tf*16+r16) ----
#pragma unroll
    for (int rf = 0; rf < 2; ++rf) {
      float al[4];
#pragma unroll
      for (int r = 0; r < 4; ++r) {
        float mx = fmaxf(fmaxf(sf[rf][0][r], sf[rf][1][r]), fmaxf(sf[rf][2][r], sf[rf][3][r]));
        mx = fmaxf(mx, __shfl_xor(mx, 1));
        mx = fmaxf(mx, __shfl_xor(mx, 2));
        mx = fmaxf(mx, __shfl_xor(mx, 4));
        mx = fmaxf(mx, __shfl_xor(mx, 8));
        mx *= SM_SCALE;
        float mn = fmaxf(mr[rf][r], mx);
        al[r] = __expf(mr[rf][r] - mn);
        mr[rf][r] = mn;
      }
      float rs[4] = {0.f, 0.f, 0.f, 0.f};
#pragma unroll
      for (int tf = 0; tf < 4; ++tf) {
#pragma unroll
        for (int r = 0; r < 4; ++r) {
          float p = __expf(sf[rf][tf][r] * SM_SCALE - mr[rf][r]);
          rs[r] += p;
          const int qrow = w * 32 + rf * 16 + hi * 4 + r;
          const int t = tf * 16 + r16;
          *(bf16_t*)((char*)lP + qrow * 128 + ((t * 2) ^ ((qrow & 7) << 4))) = (bf16_t)p;
        }
      }
#pragma unroll
      for (int r = 0; r < 4; ++r) {
        float s_ = rs[r];
        s_ += __shfl_xor(s_, 1);
        s_ += __shfl_xor(s_, 2);
        s_ += __shfl_xor(s_, 4);
        s_ += __shfl_xor(s_, 8);
        lr[rf][r] = lr[rf][r] * al[r] + s_;
      }
#pragma unroll
      for (int cf = 0; cf < 16; ++cf)
#pragma unroll
        for (int r = 0; r < 4; ++r) oacc[rf][cf][r] *= al[r];
    }

    // ---- O += P V  (P via LDS re-layout to A-operand; same-wave rows,
    //      DS is in-order per wave so no barrier needed) ----
    bf16x8 pa[2][2];
#pragma unroll
    for (int rf = 0; rf < 2; ++rf)
#pragma unroll
      for (int ks = 0; ks < 2; ++ks) {
        const int qrow = w * 32 + rf * 16 + r16;
        pa[rf][ks] = *(const bf16x8*)((const char*)lP + qrow * 128 + ((ks * 64 + hi * 16) ^ ((qrow & 7) << 4)));
      }
    const char* vbase = (const char*)lV[cur];
#pragma unroll
    for (int cf = 0; cf < 16; ++cf) {
      const int vrow = cf * 16 + r16;
      const int voff = vrow * 128;
      const int vsw = (vrow & 7) << 4;
#pragma unroll
      for (int ks = 0; ks < 2; ++ks) {
        bf16x8 vf = *(const bf16x8*)(vbase + voff + ((ks * 64 + hi * 16) ^ vsw));
        oacc[0][cf] = __builtin_amdgcn_mfma_f32_16x16x32_bf16(pa[0][ks], vf, oacc[0][cf], 0, 0, 0);
        oacc[1][cf] = __builtin_amdgcn_mfma_f32_16x16x32_bf16(pa[1][ks], vf, oacc[1][cf], 0, 0, 0);
      }
    }
    __syncthreads();
  }

  // epilogue: normalize, write per-head slice of [B*S, 1024]
#pragma unroll
  for (int rf = 0; rf < 2; ++rf) {
    float inv[4];
#pragma unroll
    for (int r = 0; r < 4; ++r) inv[r] = 1.0f / lr[rf][r];
#pragma unroll
    for (int cf = 0; cf < 16; ++cf)
#pragma unroll
      for (int r = 0; r < 4; ++r) {
        const long srow = (long)b * S_LEN + q0 + w * 32 + rf * 16 + hi * 4 + r;
        O[srow * DMODEL + h * DKV + cf * 16 + r16] = (bf16_t)(oacc[rf][cf][r] * inv[r]);
      }
  }
}

// ---------------- launch ----------------
extern "C" void kernel_launch(void* const* d_in, const int* in_sizes, int n_in,
                              void* d_out, int out_size, void* d_ws, size_t ws_size,
                              hipStream_t stream) {
  (void)in_sizes; (void)n_in; (void)out_size; (void)ws_size;
  const float* X = (const float*)d_in[0];
  const float* Wq = (const float*)d_in[1];
  const float* Wk = (const float*)d_in[2];
  const float* Wv = (const float*)d_in[3];
  const float* Wo = (const float*)d_in[4];
  float* out = (float*)d_out;

  // Workspace layout (peak 49MB). AO aliases Xb: Xb is dead after the QKV GEMM.
  char* ws = (char*)d_ws;
  bf16_t* Xb   = (bf16_t*)(ws);                       // 8192x1024   16MB (phase 1)
  bf16_t* AO   = (bf16_t*)(ws);                       // 8192x1024   16MB (phase 2, aliases Xb)
  bf16_t* Wqkv = (bf16_t*)(ws + (16l << 20));         // 1536x1024    3MB
  bf16_t* Wob  = (bf16_t*)(ws + (19l << 20));         // 1024x1024    2MB
  bf16_t* QKV  = (bf16_t*)(ws + (21l << 20));         // 8192x1536   24MB
  bf16_t* Vt   = (bf16_t*)(ws + (45l << 20));         // 2x256x4096   4MB

  const int M = 2 * S_LEN;  // 8192

  cvt_bf16<<<(M * DMODEL / 4 + 255) / 256, 256, 0, stream>>>((const float4*)X, Xb, M * DMODEL / 4);
  cvt_bf16<<<(DMODEL * DMODEL / 4 + 255) / 256, 256, 0, stream>>>((const float4*)Wq, Wqkv, DMODEL * DMODEL / 4);
  cvt_bf16<<<(DKV * DMODEL / 4 + 255) / 256, 256, 0, stream>>>((const float4*)Wk, Wqkv + 1024 * 1024, DKV * DMODEL / 4);
  cvt_bf16<<<(DKV * DMODEL / 4 + 255) / 256, 256, 0, stream>>>((const float4*)Wv, Wqkv + 1280 * 1024, DKV * DMODEL / 4);
  cvt_bf16<<<(DMODEL * DMODEL / 4 + 255) / 256, 256, 0, stream>>>((const float4*)Wo, Wob, DMODEL * DMODEL / 4);

  gemm_nt<bf16_t><<<dim3(M / 128, NQKV / 128), 256, 0, stream>>>(Xb, Wqkv, QKV, M, NQKV, DMODEL);
  transpose_v<<<dim3(S_LEN / 64, DKV / 64, 2), 256, 0, stream>>>(QKV, Vt);
  mla_attn<<<dim3(S_LEN / 128 * 8), 256, 0, stream>>>(QKV, Vt, AO);
  gemm_nt<float><<<dim3(M / 128, DMODEL / 128), 256, 0, stream>>>(AO, Wob, out, M, DMODEL, DMODEL);
}

// Round 4
// 382.215 us; speedup vs baseline: 1.3916x; 1.3916x over previous
//
#include <hip/hip_runtime.h>
#include <hip/hip_bf16.h>
#include <cstdint>

// MLA: B=2, S=4096, D=1024, H=4, dk=d_kv=256, scale=1/16.
// bf16 MFMA everywhere: QKV fused NT GEMM -> flash attention (K/V shared
// across heads) -> O projection (fp32 out).
// R2: attention 256->512 threads (8 waves, 2/SIMD) to fix 11.7% occupancy;
//     scale folded into Q (exact, 2^-4); defer-max rescale (T13, THR=8).
// R3: + s_setprio(1) around MFMA clusters (T5; waves desync between barriers).

typedef __bf16 bf16_t;
typedef __bf16 bf16x8 __attribute__((ext_vector_type(8)));
typedef float f32x4 __attribute__((ext_vector_type(4)));
typedef unsigned short u16;
typedef u16 u16x8 __attribute__((ext_vector_type(8)));

#define DEVI static __device__ __forceinline__

constexpr int S_LEN = 4096;
constexpr int NQKV = 1536;   // Q(1024) | K(256) | V(256)
constexpr int DMODEL = 1024;
constexpr int DKV = 256;

DEVI void gload_lds16(const bf16_t* g, bf16_t* l) {
  __builtin_amdgcn_global_load_lds(
      (const __attribute__((address_space(1))) void*)g,
      (__attribute__((address_space(3))) void*)l, 16, 0, 0);
}

// ---------------- fp32 -> bf16 convert (vectorized) ----------------
__global__ void cvt_bf16(const float4* __restrict__ src, bf16_t* __restrict__ dst, int n4) {
  int i = blockIdx.x * 256 + threadIdx.x;
  if (i < n4) {
    float4 v = src[i];
    bf16_t o[4] = { (bf16_t)v.x, (bf16_t)v.y, (bf16_t)v.z, (bf16_t)v.w };
    *reinterpret_cast<uint64_t*>(dst + (size_t)i * 4) = *reinterpret_cast<uint64_t*>(o);
  }
}

// ---------------- NT GEMM: C[M,N] = A[M,K] * Bw[N,K]^T ----------------
// 128x128 block, BK=32, 4 waves (each 64x64 = 4x4 frags of 16x16x32),
// global_load_lds width-16 staging, double-buffered LDS, 2 barriers/step.
template <typename OutT>
__global__ __launch_bounds__(256) void gemm_nt(
    const bf16_t* __restrict__ A, const bf16_t* __restrict__ Bw,
    OutT* __restrict__ C, int M, int N, int K) {
  __shared__ __align__(16) bf16_t lA[2][128 * 32];
  __shared__ __align__(16) bf16_t lB[2][128 * 32];
  const int tid = threadIdx.x;
  const int lane = tid & 63;
  const int w = tid >> 6;
  const int r16 = lane & 15, hi = lane >> 4;
  const int wm = (w >> 1) * 64, wn = (w & 1) * 64;
  const long bm = (long)blockIdx.x * 128;
  const long bn = (long)blockIdx.y * 128;

  f32x4 acc[4][4] = {};

  auto stageAB = [&](int buf, int k0) {
#pragma unroll
    for (int c = 0; c < 2; ++c) {
      const int chunk = w + c * 4;           // 8 chunks of 1KB per tile
      const int row = chunk * 16 + (lane >> 2);
      const int kk = (lane & 3) * 8;
      gload_lds16(A + (bm + row) * (long)K + k0 + kk, &lA[buf][chunk * 512]);
      gload_lds16(Bw + (bn + row) * (long)K + k0 + kk, &lB[buf][chunk * 512]);
    }
  };

  const int nk = K >> 5;
  stageAB(0, 0);
  for (int kt = 0; kt < nk; ++kt) {
    const int cur = kt & 1;
    __syncthreads();                       // staging of cur complete (vmcnt drain)
    if (kt + 1 < nk) stageAB(cur ^ 1, (kt + 1) * 32);
    const bf16_t* la = lA[cur];
    const bf16_t* lb = lB[cur];
    bf16x8 af[4], bq[4];
#pragma unroll
    for (int i = 0; i < 4; ++i)
      af[i] = *(const bf16x8*)&la[(wm + i * 16 + r16) * 32 + hi * 8];
#pragma unroll
    for (int j = 0; j < 4; ++j)
      bq[j] = *(const bf16x8*)&lb[(wn + j * 16 + r16) * 32 + hi * 8];
    __builtin_amdgcn_s_setprio(1);
#pragma unroll
    for (int i = 0; i < 4; ++i)
#pragma unroll
      for (int j = 0; j < 4; ++j)
        acc[i][j] = __builtin_amdgcn_mfma_f32_16x16x32_bf16(af[i], bq[j], acc[i][j], 0, 0, 0);
    __builtin_amdgcn_s_setprio(0);
    __syncthreads();                       // all reads of cur done before restage
  }

#pragma unroll
  for (int i = 0; i < 4; ++i)
#pragma unroll
    for (int j = 0; j < 4; ++j)
#pragma unroll
      for (int r = 0; r < 4; ++r) {
        long row = bm + wm + i * 16 + hi * 4 + r;
        long col = bn + wn + j * 16 + r16;
        C[row * N + col] = (OutT)acc[i][j][r];
      }
}

// ---------------- V transpose: Vt[b][d][t] = QKV[b*S+t][1280+d] ----------------
__global__ void transpose_v(const bf16_t* __restrict__ QKV, bf16_t* __restrict__ Vt) {
  __shared__ u16 tile[64][68];
  const int t0 = blockIdx.x * 64, d0 = blockIdx.y * 64, b = blockIdx.z;
  const int tid = threadIdx.x;
  const int r = tid >> 3, c8 = tid & 7;
#pragma unroll
  for (int p = 0; p < 2; ++p) {
    const int tr = p * 32 + r;
    const u16* gp = (const u16*)QKV + (size_t)(b * S_LEN + t0 + tr) * NQKV + 1280 + d0 + c8 * 8;
    u16x8 v = *(const u16x8*)gp;
#pragma unroll
    for (int j = 0; j < 8; ++j) tile[tr][c8 * 8 + j] = v[j];
  }
  __syncthreads();
#pragma unroll
  for (int p = 0; p < 2; ++p) {
    const int dr = p * 32 + r;
    u16x8 v;
#pragma unroll
    for (int j = 0; j < 8; ++j) v[j] = tile[c8 * 8 + j][dr];
    *(u16x8*)((u16*)Vt + (size_t)(b * DKV + d0 + dr) * S_LEN + t0 + c8 * 8) = v;
  }
}

// ---------------- Flash attention ----------------
// 1D grid of 256 blocks; bh = id%8 so all q-blocks of one (b,h) share an XCD.
// Block: 128 q-rows, 8 waves x 16 rows (512 thr -> 2 waves/SIMD). K/V tiles of
// 64 t-rows double-buffered in LDS, XOR-swizzled (byte ^= (row&7)<<4) with
// inverse-swizzled global_load_lds source (guide rule #21).
// Q is pre-scaled by 2^-4 (exact in bf16) so softmax needs no scale.
// Defer-max (T13): skip O/l rescale while tile max <= m + 8.
__global__ __launch_bounds__(512, 1) void mla_attn(
    const bf16_t* __restrict__ QKV, const bf16_t* __restrict__ Vt,
    bf16_t* __restrict__ O) {
  __shared__ __align__(16) bf16_t lK[2][64 * 256];   // [t][d] swizzled, 32KB each
  __shared__ __align__(16) bf16_t lV[2][256 * 64];   // [d][t] swizzled, 32KB each
  __shared__ __align__(16) bf16_t lP[128 * 64];      // [q][t] swizzled, 16KB

  const int tid = threadIdx.x, lane = tid & 63, w = tid >> 6;  // w in [0,8)
  const int r16 = lane & 15, hi = lane >> 4;
  const int bh = blockIdx.x & 7;          // XCD-locality: same (b,h) -> same XCD
  const int b = bh >> 2, h = bh & 3;
  const int q0 = (blockIdx.x >> 3) * 128;

  auto stageK = [&](int buf, int t0) {
#pragma unroll
    for (int c = 0; c < 4; ++c) {
      const int chunk = w * 4 + c;               // 32 chunks of 1KB (2 rows)
      const int row = chunk * 2 + (lane >> 5);
      const int gslot = (lane & 31) ^ (row & 7); // inverse swizzle on source
      gload_lds16(QKV + ((long)(b * S_LEN + t0 + row)) * NQKV + 1024 + gslot * 8,
                  &lK[buf][chunk * 512]);
    }
  };
  auto stageV = [&](int buf, int t0) {
#pragma unroll
    for (int c = 0; c < 4; ++c) {
      const int chunk = w * 4 + c;               // 32 chunks of 1KB (8 d-rows)
      const int row = chunk * 8 + (lane >> 3);
      const int gslot = (lane & 7) ^ (row & 7);
      gload_lds16(Vt + ((long)(b * DKV + row)) * S_LEN + t0 + gslot * 8,
                  &lV[buf][chunk * 512]);
    }
  };

  // Q fragments in registers: 16 rows/wave, full dk=256; pre-scale by 2^-4.
  bf16x8 qa[8];
  {
    const bf16_t* qrow = QKV + ((long)(b * S_LEN + q0 + w * 16 + r16)) * NQKV + h * DKV;
#pragma unroll
    for (int ks = 0; ks < 8; ++ks) {
      bf16x8 v = *(const bf16x8*)(qrow + ks * 32 + hi * 8);
#pragma unroll
      for (int j = 0; j < 8; ++j) v[j] = (bf16_t)((float)v[j] * 0.0625f);
      qa[ks] = v;
    }
  }

  f32x4 oacc[16] = {};
  float mr[4], lr[4];
#pragma unroll
  for (int r = 0; r < 4; ++r) { mr[r] = -3.0e38f; lr[r] = 0.f; }

  stageK(0, 0);
  stageV(0, 0);

  const int nst = S_LEN / 64;
  for (int kt = 0; kt < nst; ++kt) {
    const int cur = kt & 1;
    __syncthreads();
    if (kt + 1 < nst) { stageK(cur ^ 1, (kt + 1) * 64); stageV(cur ^ 1, (kt + 1) * 64); }

    // ---- S = Q K^T (rows q, cols t); Q pre-scaled ----
    f32x4 sf[4] = {};
    const char* kbase = (const char*)lK[cur];
    __builtin_amdgcn_s_setprio(1);
#pragma unroll
    for (int tf = 0; tf < 4; ++tf) {
      const int row = tf * 16 + r16;
      const int rowoff = row * 512;
      const int sw = (row & 7) << 4;
#pragma unroll
      for (int ks = 0; ks < 8; ++ks) {
        bf16x8 kf = *(const bf16x8*)(kbase + rowoff + ((ks * 64 + hi * 16) ^ sw));
        sf[tf] = __builtin_amdgcn_mfma_f32_16x16x32_bf16(qa[ks], kf, sf[tf], 0, 0, 0);
      }
    }
    __builtin_amdgcn_s_setprio(0);

    // ---- online softmax, defer-max (lane holds rows hi*4+r, col tf*16+r16) ----
    float mx[4];
    float need = -3.0e38f;
#pragma unroll
    for (int r = 0; r < 4; ++r) {
      float m_ = fmaxf(fmaxf(sf[0][r], sf[1][r]), fmaxf(sf[2][r], sf[3][r]));
      m_ = fmaxf(m_, __shfl_xor(m_, 1));
      m_ = fmaxf(m_, __shfl_xor(m_, 2));
      m_ = fmaxf(m_, __shfl_xor(m_, 4));
      m_ = fmaxf(m_, __shfl_xor(m_, 8));
      mx[r] = m_;
      need = fmaxf(need, m_ - mr[r]);
    }
    if (__any(need > 8.0f)) {            // wave-uniform rescale (rare)
#pragma unroll
      for (int r = 0; r < 4; ++r) {
        float mn = fmaxf(mr[r], mx[r]);
        float al = __expf(mr[r] - mn);
        mr[r] = mn;
        lr[r] *= al;
#pragma unroll
        for (int cf = 0; cf < 16; ++cf) oacc[cf][r] *= al;
      }
    }
    float rs[4] = {0.f, 0.f, 0.f, 0.f};
#pragma unroll
    for (int tf = 0; tf < 4; ++tf) {
#pragma unroll
      for (int r = 0; r < 4; ++r) {
        float p = __expf(sf[tf][r] - mr[r]);
        rs[r] += p;
        const int qrow = w * 16 + hi * 4 + r;
        const int t = tf * 16 + r16;
        *(bf16_t*)((char*)lP + qrow * 128 + ((t * 2) ^ ((qrow & 7) << 4))) = (bf16_t)p;
      }
    }
#pragma unroll
    for (int r = 0; r < 4; ++r) {
      float s_ = rs[r];
      s_ += __shfl_xor(s_, 1);
      s_ += __shfl_xor(s_, 2);
      s_ += __shfl_xor(s_, 4);
      s_ += __shfl_xor(s_, 8);
      lr[r] += s_;
    }

    // ---- O += P V  (P via LDS re-layout; same-wave rows, DS in-order) ----
    bf16x8 pa[2];
#pragma unroll
    for (int ks = 0; ks < 2; ++ks) {
      const int qrow = w * 16 + r16;
      pa[ks] = *(const bf16x8*)((const char*)lP + qrow * 128 + ((ks * 64 + hi * 16) ^ ((qrow & 7) << 4)));
    }
    const char* vbase = (const char*)lV[cur];
    __builtin_amdgcn_s_setprio(1);
#pragma unroll
    for (int cf = 0; cf < 16; ++cf) {
      const int vrow = cf * 16 + r16;
      const int voff = vrow * 128;
      const int vsw = (vrow & 7) << 4;
#pragma unroll
      for (int ks = 0; ks < 2; ++ks) {
        bf16x8 vf = *(const bf16x8*)(vbase + voff + ((ks * 64 + hi * 16) ^ vsw));
        oacc[cf] = __builtin_amdgcn_mfma_f32_16x16x32_bf16(pa[ks], vf, oacc[cf], 0, 0, 0);
      }
    }
    __builtin_amdgcn_s_setprio(0);
    __syncthreads();
  }

  // epilogue: normalize, write per-head slice of [B*S, 1024]
  {
    float inv[4];
#pragma unroll
    for (int r = 0; r < 4; ++r) inv[r] = 1.0f / lr[r];
#pragma unroll
    for (int cf = 0; cf < 16; ++cf)
#pragma unroll
      for (int r = 0; r < 4; ++r) {
        const long srow = (long)b * S_LEN + q0 + w * 16 + hi * 4 + r;
        O[srow * DMODEL + h * DKV + cf * 16 + r16] = (bf16_t)(oacc[cf][r] * inv[r]);
      }
  }
}

// ---------------- launch ----------------
extern "C" void kernel_launch(void* const* d_in, const int* in_sizes, int n_in,
                              void* d_out, int out_size, void* d_ws, size_t ws_size,
                              hipStream_t stream) {
  (void)in_sizes; (void)n_in; (void)out_size; (void)ws_size;
  const float* X = (const float*)d_in[0];
  const float* Wq = (const float*)d_in[1];
  const float* Wk = (const float*)d_in[2];
  const float* Wv = (const float*)d_in[3];
  const float* Wo = (const float*)d_in[4];
  float* out = (float*)d_out;

  // Workspace layout (peak 49MB). AO aliases Xb: Xb is dead after the QKV GEMM.
  char* ws = (char*)d_ws;
  bf16_t* Xb   = (bf16_t*)(ws);                       // 8192x1024   16MB (phase 1)
  bf16_t* AO   = (bf16_t*)(ws);                       // 8192x1024   16MB (phase 2, aliases Xb)
  bf16_t* Wqkv = (bf16_t*)(ws + (16l << 20));         // 1536x1024    3MB
  bf16_t* Wob  = (bf16_t*)(ws + (19l << 20));         // 1024x1024    2MB
  bf16_t* QKV  = (bf16_t*)(ws + (21l << 20));         // 8192x1536   24MB
  bf16_t* Vt   = (bf16_t*)(ws + (45l << 20));         // 2x256x4096   4MB

  const int M = 2 * S_LEN;  // 8192

  cvt_bf16<<<(M * DMODEL / 4 + 255) / 256, 256, 0, stream>>>((const float4*)X, Xb, M * DMODEL / 4);
  cvt_bf16<<<(DMODEL * DMODEL / 4 + 255) / 256, 256, 0, stream>>>((const float4*)Wq, Wqkv, DMODEL * DMODEL / 4);
  cvt_bf16<<<(DKV * DMODEL / 4 + 255) / 256, 256, 0, stream>>>((const float4*)Wk, Wqkv + 1024 * 1024, DKV * DMODEL / 4);
  cvt_bf16<<<(DKV * DMODEL / 4 + 255) / 256, 256, 0, stream>>>((const float4*)Wv, Wqkv + 1280 * 1024, DKV * DMODEL / 4);
  cvt_bf16<<<(DMODEL * DMODEL / 4 + 255) / 256, 256, 0, stream>>>((const float4*)Wo, Wob, DMODEL * DMODEL / 4);

  gemm_nt<bf16_t><<<dim3(M / 128, NQKV / 128), 256, 0, stream>>>(Xb, Wqkv, QKV, M, NQKV, DMODEL);
  transpose_v<<<dim3(S_LEN / 64, DKV / 64, 2), 256, 0, stream>>>(QKV, Vt);
  mla_attn<<<dim3(S_LEN / 128 * 8), 512, 0, stream>>>(QKV, Vt, AO);
  gemm_nt<float><<<dim3(M / 128, DMODEL / 128), 256, 0, stream>>>(AO, Wob, out, M, DMODEL, DMODEL);
}